// Round 1
// baseline (356.834 us; speedup 1.0000x reference)
//
#include <hip/hip_runtime.h>
#include <hip/hip_bf16.h>

// Liquid NN: h' = -alpha*h + beta*tanh(x_t @ W_fc^T + b_fc + gamma*h), dopri5 -> RK4 fixed-step
// B=256 S=64 I=256 H=1024 O=10, t in [0,1], input switches every 1/64.

#define NB 256
#define NS 64
#define NI 256
#define NH 1024
#define NO 10
#define KSUB 8   // RK4 substeps per input interval; dt = 1/(NS*KSUB) = 1/512

// ---------------------------------------------------------------------------
// Kernel 1: U[s*NB + b][h] = dot(x[b][s][:], W_fc[h][:]) + b_fc[h]
// M = NS*NB = 16384, N = NH = 1024, K = NI = 256.  fp32 vector-ALU GEMM.
// 64x64 tile, BK=16, 256 threads, 4x4 outputs/thread, LDS layout [k][m]/[k][n].
// ---------------------------------------------------------------------------
__global__ __launch_bounds__(256) void fc_gemm(
    const float* __restrict__ x, const float* __restrict__ Wfc,
    const float* __restrict__ bfc, float* __restrict__ U)
{
    __shared__ float As[16][64];  // [k][m]
    __shared__ float Bs[16][64];  // [k][n]

    const int t  = threadIdx.x;
    const int m0 = blockIdx.y * 64;   // out-row tile (r = s*NB + b)
    const int n0 = blockIdx.x * 64;   // h tile
    const int ty = t >> 4;            // 0..15
    const int tx = t & 15;            // 0..15

    float acc[4][4];
#pragma unroll
    for (int i = 0; i < 4; ++i)
#pragma unroll
        for (int j = 0; j < 4; ++j) acc[i][j] = 0.f;

    // staging assignment: thread t loads 4 consecutive k of one row
    const int lrow = t >> 2;          // 0..63 (tile row)
    const int lk4  = (t & 3) * 4;     // 0,4,8,12

    // out-row r = s*NB + b  ->  input row = b*NS + s
    const int r     = m0 + lrow;
    const int s_idx = r >> 8;         // r / 256
    const int b_idx = r & 255;        // r % 256
    const float* xrow = x   + (size_t)(b_idx * NS + s_idx) * NI;
    const float* wrow = Wfc + (size_t)(n0 + lrow) * NI;

    for (int k0 = 0; k0 < NI; k0 += 16) {
        float4 av = *(const float4*)(xrow + k0 + lk4);
        float4 bv = *(const float4*)(wrow + k0 + lk4);
        __syncthreads();   // protect previous iteration's reads
        As[lk4 + 0][lrow] = av.x; As[lk4 + 1][lrow] = av.y;
        As[lk4 + 2][lrow] = av.z; As[lk4 + 3][lrow] = av.w;
        Bs[lk4 + 0][lrow] = bv.x; Bs[lk4 + 1][lrow] = bv.y;
        Bs[lk4 + 2][lrow] = bv.z; Bs[lk4 + 3][lrow] = bv.w;
        __syncthreads();
#pragma unroll
        for (int kk = 0; kk < 16; ++kk) {
            float4 a = *(const float4*)&As[kk][ty * 4];  // broadcast across tx
            float4 b = *(const float4*)&Bs[kk][tx * 4];  // 2-way (free)
            acc[0][0] = fmaf(a.x, b.x, acc[0][0]);
            acc[0][1] = fmaf(a.x, b.y, acc[0][1]);
            acc[0][2] = fmaf(a.x, b.z, acc[0][2]);
            acc[0][3] = fmaf(a.x, b.w, acc[0][3]);
            acc[1][0] = fmaf(a.y, b.x, acc[1][0]);
            acc[1][1] = fmaf(a.y, b.y, acc[1][1]);
            acc[1][2] = fmaf(a.y, b.z, acc[1][2]);
            acc[1][3] = fmaf(a.y, b.w, acc[1][3]);
            acc[2][0] = fmaf(a.z, b.x, acc[2][0]);
            acc[2][1] = fmaf(a.z, b.y, acc[2][1]);
            acc[2][2] = fmaf(a.z, b.z, acc[2][2]);
            acc[2][3] = fmaf(a.z, b.w, acc[2][3]);
            acc[3][0] = fmaf(a.w, b.x, acc[3][0]);
            acc[3][1] = fmaf(a.w, b.y, acc[3][1]);
            acc[3][2] = fmaf(a.w, b.z, acc[3][2]);
            acc[3][3] = fmaf(a.w, b.w, acc[3][3]);
        }
    }

    float4 bb = *(const float4*)(bfc + n0 + tx * 4);
#pragma unroll
    for (int i = 0; i < 4; ++i) {
        const size_t row = (size_t)(m0 + ty * 4 + i);
        float4 v = make_float4(acc[i][0] + bb.x, acc[i][1] + bb.y,
                               acc[i][2] + bb.z, acc[i][3] + bb.w);
        *(float4*)(U + row * NH + n0 + tx * 4) = v;
    }
}

// ---------------------------------------------------------------------------
// Kernel 2: per-element RK4 integration of the scalar ODE.
//   h' = -a*h + be*tanh(u + ga*h), u piecewise-constant per interval.
// One thread per (b,h); 64 intervals x KSUB RK4 substeps.
// ---------------------------------------------------------------------------
__device__ __forceinline__ float f_eval(float h, float u, float a, float be, float ga)
{
    float z  = fmaf(ga, h, u);
    float e  = __expf(z + z);                                  // e^{2z}; inf/0 at extremes OK
    float th = fmaf(-2.0f, __builtin_amdgcn_rcpf(e + 1.0f), 1.0f);  // tanh(z)
    return fmaf(-a, h, be * th);
}

__global__ __launch_bounds__(256) void ode_kernel(
    const float* __restrict__ U, const float* __restrict__ alpha,
    const float* __restrict__ beta, const float* __restrict__ gamma,
    float* __restrict__ hout)
{
    const int idx = blockIdx.x * 256 + threadIdx.x;  // b*NH + h
    const int hid = idx & (NH - 1);
    const float a  = alpha[hid];
    const float be = beta[hid];
    const float ga = gamma[hid];
    const float dt = 1.0f / (float)(NS * KSUB);

    float h = 0.f;
    float u = U[idx];
#pragma unroll 1
    for (int s = 0; s < NS; ++s) {
        const int snext = (s + 1 < NS) ? s + 1 : NS - 1;
        const float u_next = U[(size_t)snext * (NB * NH) + idx];  // prefetch next interval
#pragma unroll
        for (int k = 0; k < KSUB; ++k) {
            float k1 = f_eval(h, u, a, be, ga);
            float k2 = f_eval(fmaf(0.5f * dt, k1, h), u, a, be, ga);
            float k3 = f_eval(fmaf(0.5f * dt, k2, h), u, a, be, ga);
            float k4 = f_eval(fmaf(dt, k3, h), u, a, be, ga);
            h = fmaf(dt * (1.0f / 6.0f), k1 + 2.0f * (k2 + k3) + k4, h);
        }
        u = u_next;
    }
    hout[idx] = h;
}

// ---------------------------------------------------------------------------
// Kernel 3: out[b][o] = dot(h_final[b], W_out[o]) + b_out[o].  256 blocks.
// ---------------------------------------------------------------------------
__global__ __launch_bounds__(256) void out_gemv(
    const float* __restrict__ hfin, const float* __restrict__ Wout,
    const float* __restrict__ bout, float* __restrict__ out)
{
    __shared__ float red[4][NO];
    const int b = blockIdx.x;
    const int t = threadIdx.x;

    const float h0 = hfin[b * NH + t];
    const float h1 = hfin[b * NH + t + 256];
    const float h2 = hfin[b * NH + t + 512];
    const float h3 = hfin[b * NH + t + 768];

    float acc[NO];
#pragma unroll
    for (int o = 0; o < NO; ++o) {
        const float* wr = Wout + (size_t)o * NH + t;
        acc[o] = h0 * wr[0] + h1 * wr[256] + h2 * wr[512] + h3 * wr[768];
    }
#pragma unroll
    for (int o = 0; o < NO; ++o)
#pragma unroll
        for (int off = 32; off > 0; off >>= 1)
            acc[o] += __shfl_down(acc[o], off, 64);

    const int wid = t >> 6, lane = t & 63;
    if (lane == 0)
#pragma unroll
        for (int o = 0; o < NO; ++o) red[wid][o] = acc[o];
    __syncthreads();
    if (t < NO)
        out[b * NO + t] = red[0][t] + red[1][t] + red[2][t] + red[3][t] + bout[t];
}

// ---------------------------------------------------------------------------
extern "C" void kernel_launch(void* const* d_in, const int* in_sizes, int n_in,
                              void* d_out, int out_size, void* d_ws, size_t ws_size,
                              hipStream_t stream)
{
    const float* x     = (const float*)d_in[0];
    const float* Wfc   = (const float*)d_in[1];
    const float* bfc   = (const float*)d_in[2];
    const float* alpha = (const float*)d_in[3];
    const float* beta  = (const float*)d_in[4];
    const float* gamma = (const float*)d_in[5];
    const float* Wout  = (const float*)d_in[6];
    const float* bout  = (const float*)d_in[7];
    float* out = (float*)d_out;

    // workspace: U [NS][NB][NH] fp32 (64 MiB) + h_final [NB][NH] (1 MiB)
    float* U    = (float*)d_ws;
    float* hfin = U + (size_t)NS * NB * NH;

    dim3 g1(NH / 64, (NS * NB) / 64);
    fc_gemm<<<g1, 256, 0, stream>>>(x, Wfc, bfc, U);
    ode_kernel<<<(NB * NH) / 256, 256, 0, stream>>>(U, alpha, beta, gamma, hfin);
    out_gemv<<<NB, 256, 0, stream>>>(hfin, Wout, bout, out);
}

// Round 2
// 228.155 us; speedup vs baseline: 1.5640x; 1.5640x over previous
//
#include <hip/hip_runtime.h>
#include <hip/hip_bf16.h>

// Liquid NN: h' = -alpha*h + beta*tanh(x_t @ W_fc^T + b_fc + gamma*h), dopri5 -> RK4 fixed-step
// B=256 S=64 I=256 H=1024 O=10, t in [0,1], input switches every 1/64.

#define NB 256
#define NS 64
#define NI 256
#define NH 1024
#define NO 10
#define KSUB 2   // RK4 substeps per input interval; dt = 1/(NS*KSUB) = 1/128
                 // error budget: (|lambda|dt)^5/120 per step ~ 6e-8, global ~1e-5 rel,
                 // amplified ~27x by growing modes -> ~3e-4 << 7.1e-3 threshold.

// ---------------------------------------------------------------------------
// Kernel 1: U[s*NB + b][h] = dot(x[b][s][:], W_fc[h][:]) + b_fc[h]
// M = NS*NB = 16384, N = NH = 1024, K = NI = 256.  fp32 vector-ALU GEMM.
// 128x128 tile, BK=16, 256 threads, 8x8 outputs/thread, LDS layout [k][m]/[k][n].
// ---------------------------------------------------------------------------
__global__ __launch_bounds__(256, 2) void fc_gemm(
    const float* __restrict__ x, const float* __restrict__ Wfc,
    const float* __restrict__ bfc, float* __restrict__ U)
{
    __shared__ float As[16][128];  // [k][m]
    __shared__ float Bs[16][128];  // [k][n]

    const int t  = threadIdx.x;
    const int m0 = blockIdx.y * 128;  // out-row tile (r = s*NB + b)
    const int n0 = blockIdx.x * 128;  // h tile
    const int ty = t >> 4;            // 0..15  -> output rows ty*8..+7
    const int tx = t & 15;            // 0..15  -> output cols tx*8..+7

    float acc[8][8];
#pragma unroll
    for (int i = 0; i < 8; ++i)
#pragma unroll
        for (int j = 0; j < 8; ++j) acc[i][j] = 0.f;

    // staging: thread t loads float4 at k-offset lk4 of tile-rows lrow and lrow+64
    const int lrow = t >> 2;          // 0..63
    const int lk4  = (t & 3) * 4;     // 0,4,8,12

    // out-row r = s*NB + b  ->  input row = b*NS + s ; tile spans one s (128|256)
    const int s_idx = m0 >> 8;
    const int b_idx = m0 & 255;
    const float* xrow0 = x + ((size_t)((b_idx + lrow) * NS + s_idx)) * NI;
    const float* xrow1 = x + ((size_t)((b_idx + lrow + 64) * NS + s_idx)) * NI;
    const float* wrow0 = Wfc + (size_t)(n0 + lrow) * NI;
    const float* wrow1 = Wfc + (size_t)(n0 + lrow + 64) * NI;

    for (int k0 = 0; k0 < NI; k0 += 16) {
        float4 a0 = *(const float4*)(xrow0 + k0 + lk4);
        float4 a1 = *(const float4*)(xrow1 + k0 + lk4);
        float4 b0 = *(const float4*)(wrow0 + k0 + lk4);
        float4 b1 = *(const float4*)(wrow1 + k0 + lk4);
        __syncthreads();   // protect previous iteration's reads
        As[lk4 + 0][lrow] = a0.x; As[lk4 + 1][lrow] = a0.y;
        As[lk4 + 2][lrow] = a0.z; As[lk4 + 3][lrow] = a0.w;
        As[lk4 + 0][lrow + 64] = a1.x; As[lk4 + 1][lrow + 64] = a1.y;
        As[lk4 + 2][lrow + 64] = a1.z; As[lk4 + 3][lrow + 64] = a1.w;
        Bs[lk4 + 0][lrow] = b0.x; Bs[lk4 + 1][lrow] = b0.y;
        Bs[lk4 + 2][lrow] = b0.z; Bs[lk4 + 3][lrow] = b0.w;
        Bs[lk4 + 0][lrow + 64] = b1.x; Bs[lk4 + 1][lrow + 64] = b1.y;
        Bs[lk4 + 2][lrow + 64] = b1.z; Bs[lk4 + 3][lrow + 64] = b1.w;
        __syncthreads();
#pragma unroll
        for (int kk = 0; kk < 16; ++kk) {
            float4 aL = *(const float4*)&As[kk][ty * 8];
            float4 aH = *(const float4*)&As[kk][ty * 8 + 4];
            float4 bL = *(const float4*)&Bs[kk][tx * 8];
            float4 bH = *(const float4*)&Bs[kk][tx * 8 + 4];
            float av[8] = {aL.x, aL.y, aL.z, aL.w, aH.x, aH.y, aH.z, aH.w};
            float bv[8] = {bL.x, bL.y, bL.z, bL.w, bH.x, bH.y, bH.z, bH.w};
#pragma unroll
            for (int i = 0; i < 8; ++i)
#pragma unroll
                for (int j = 0; j < 8; ++j)
                    acc[i][j] = fmaf(av[i], bv[j], acc[i][j]);
        }
    }

    float4 bbL = *(const float4*)(bfc + n0 + tx * 8);
    float4 bbH = *(const float4*)(bfc + n0 + tx * 8 + 4);
#pragma unroll
    for (int i = 0; i < 8; ++i) {
        const size_t row = (size_t)(m0 + ty * 8 + i);
        float4 vL = make_float4(acc[i][0] + bbL.x, acc[i][1] + bbL.y,
                                acc[i][2] + bbL.z, acc[i][3] + bbL.w);
        float4 vH = make_float4(acc[i][4] + bbH.x, acc[i][5] + bbH.y,
                                acc[i][6] + bbH.z, acc[i][7] + bbH.w);
        *(float4*)(U + row * NH + n0 + tx * 8)     = vL;
        *(float4*)(U + row * NH + n0 + tx * 8 + 4) = vH;
    }
}

// ---------------------------------------------------------------------------
// Kernel 2: per-element RK4 integration of the scalar ODE.
//   h' = -a*h + be*tanh(u + ga*h), u piecewise-constant per interval.
// c = 2*log2e*ga (hoisted), d = 2*log2e*u (per interval):
//   tanh(u+ga*h) = 1 - 2/(1 + exp2(c*h + d))
// ---------------------------------------------------------------------------
__device__ __forceinline__ float f_eval(float h, float c, float d, float na, float be)
{
    float z2 = fmaf(c, h, d);
#if __has_builtin(__builtin_amdgcn_exp2f)
    float e = __builtin_amdgcn_exp2f(z2);
#else
    float e = __expf(0.69314718056f * z2);
#endif
    float th = fmaf(-2.0f, __builtin_amdgcn_rcpf(e + 1.0f), 1.0f);
    return fmaf(na, h, be * th);
}

__global__ __launch_bounds__(256) void ode_kernel(
    const float* __restrict__ U, const float* __restrict__ alpha,
    const float* __restrict__ beta, const float* __restrict__ gamma,
    float* __restrict__ hout)
{
    const int idx = blockIdx.x * 256 + threadIdx.x;  // b*NH + h
    const int hid = idx & (NH - 1);
    const float na = -alpha[hid];
    const float be = beta[hid];
    const float L2E2 = 2.8853900817779268f;          // 2*log2(e)
    const float c  = L2E2 * gamma[hid];
    const float dt  = 1.0f / (float)(NS * KSUB);
    const float hdt = 0.5f * dt;
    const float dt6 = dt * (1.0f / 6.0f);

    float h = 0.f;
    float u = U[idx];
#pragma unroll 1
    for (int s = 0; s < NS; ++s) {
        const int snext = (s + 1 < NS) ? s + 1 : NS - 1;
        const float u_next = U[(size_t)snext * (NB * NH) + idx];  // prefetch next interval
        const float d = L2E2 * u;
#pragma unroll
        for (int k = 0; k < KSUB; ++k) {
            float k1 = f_eval(h, c, d, na, be);
            float k2 = f_eval(fmaf(hdt, k1, h), c, d, na, be);
            float k3 = f_eval(fmaf(hdt, k2, h), c, d, na, be);
            float k4 = f_eval(fmaf(dt, k3, h), c, d, na, be);
            float t1 = k2 + k3;
            float t2 = k1 + k4;
            h = fmaf(dt6, fmaf(2.0f, t1, t2), h);
        }
        u = u_next;
    }
    hout[idx] = h;
}

// ---------------------------------------------------------------------------
// Kernel 3: out[b][o] = dot(h_final[b], W_out[o]) + b_out[o].  256 blocks.
// ---------------------------------------------------------------------------
__global__ __launch_bounds__(256) void out_gemv(
    const float* __restrict__ hfin, const float* __restrict__ Wout,
    const float* __restrict__ bout, float* __restrict__ out)
{
    __shared__ float red[4][NO];
    const int b = blockIdx.x;
    const int t = threadIdx.x;

    const float h0 = hfin[b * NH + t];
    const float h1 = hfin[b * NH + t + 256];
    const float h2 = hfin[b * NH + t + 512];
    const float h3 = hfin[b * NH + t + 768];

    float acc[NO];
#pragma unroll
    for (int o = 0; o < NO; ++o) {
        const float* wr = Wout + (size_t)o * NH + t;
        acc[o] = h0 * wr[0] + h1 * wr[256] + h2 * wr[512] + h3 * wr[768];
    }
#pragma unroll
    for (int o = 0; o < NO; ++o)
#pragma unroll
        for (int off = 32; off > 0; off >>= 1)
            acc[o] += __shfl_down(acc[o], off, 64);

    const int wid = t >> 6, lane = t & 63;
    if (lane == 0)
#pragma unroll
        for (int o = 0; o < NO; ++o) red[wid][o] = acc[o];
    __syncthreads();
    if (t < NO)
        out[b * NO + t] = red[0][t] + red[1][t] + red[2][t] + red[3][t] + bout[t];
}

// ---------------------------------------------------------------------------
extern "C" void kernel_launch(void* const* d_in, const int* in_sizes, int n_in,
                              void* d_out, int out_size, void* d_ws, size_t ws_size,
                              hipStream_t stream)
{
    const float* x     = (const float*)d_in[0];
    const float* Wfc   = (const float*)d_in[1];
    const float* bfc   = (const float*)d_in[2];
    const float* alpha = (const float*)d_in[3];
    const float* beta  = (const float*)d_in[4];
    const float* gamma = (const float*)d_in[5];
    const float* Wout  = (const float*)d_in[6];
    const float* bout  = (const float*)d_in[7];
    float* out = (float*)d_out;

    // workspace: U [NS][NB][NH] fp32 (64 MiB) + h_final [NB][NH] (1 MiB)
    float* U    = (float*)d_ws;
    float* hfin = U + (size_t)NS * NB * NH;

    dim3 g1(NH / 128, (NS * NB) / 128);
    fc_gemm<<<g1, 256, 0, stream>>>(x, Wfc, bfc, U);
    ode_kernel<<<(NB * NH) / 256, 256, 0, stream>>>(U, alpha, beta, gamma, hfin);
    out_gemv<<<NB, 256, 0, stream>>>(hfin, Wout, bout, out);
}

// Round 3
// 216.926 us; speedup vs baseline: 1.6450x; 1.0518x over previous
//
#include <hip/hip_runtime.h>
#include <hip/hip_bf16.h>

// Liquid NN: h' = -alpha*h + beta*tanh(x_t @ W_fc^T + b_fc + gamma*h)
// B=256 S=64 I=256 H=1024 O=10, t in [0,1], input switches every 1/64.
// Pipeline: split(fp32->bf16 hi/lo) -> MFMA GEMM (K'=768) -> RK4 ODE -> out GEMV.

#define NB 256
#define NS 64
#define NI 256
#define NH 1024
#define NO 10
#define KSUB 2   // RK4 substeps per interval; truncation << fp32 noise floor (absmax
                 // identical at KSUB=8 and 2). KSUB=1 risky: units with beta*gamma~10
                 // amplify the ~1.7e-4 truncation toward the 7.1e-3 threshold.

typedef __attribute__((ext_vector_type(8))) short short8;
typedef __attribute__((ext_vector_type(4))) float f32x4;

// ---------------------------------------------------------------------------
// Kernel 0: bf16 hi/lo split. x [b][s][k] -> xhi/xlo [s*NB+b][k] (transposed),
// Wfc [h][k] -> whi/wlo [h][k]. v = hi + lo with |v - hi - lo| ~ 2^-17 |v|.
// ---------------------------------------------------------------------------
__device__ __forceinline__ void split1(float v, unsigned short& h, unsigned short& l)
{
    __hip_bfloat16 bh = __float2bfloat16(v);
    float fh = __bfloat162float(bh);
    __hip_bfloat16 bl = __float2bfloat16(v - fh);   // v - fh exact in fp32
    h = __builtin_bit_cast(unsigned short, bh);
    l = __builtin_bit_cast(unsigned short, bl);
}

__global__ __launch_bounds__(256) void split_kernel(
    const float* __restrict__ x, const float* __restrict__ Wfc,
    __hip_bfloat16* __restrict__ xhi, __hip_bfloat16* __restrict__ xlo,
    __hip_bfloat16* __restrict__ whi, __hip_bfloat16* __restrict__ wlo)
{
    const int bid = blockIdx.x;
    if (bid < 4096) {   // x: 256*64*256 = 4.19M elements, 4 per thread
        const size_t e = ((size_t)bid * 256 + threadIdx.x) * 4;
        const int k  = (int)(e & (NI - 1));
        const int bs = (int)(e >> 8);          // b*NS + s
        const int s  = bs & (NS - 1);
        const int b  = bs >> 6;
        const size_t r = ((size_t)(s * NB + b)) * NI + k;
        float4 v = *(const float4*)(x + e);
        ushort4 h, l;
        split1(v.x, h.x, l.x); split1(v.y, h.y, l.y);
        split1(v.z, h.z, l.z); split1(v.w, h.w, l.w);
        *(ushort4*)((unsigned short*)xhi + r) = h;
        *(ushort4*)((unsigned short*)xlo + r) = l;
    } else {            // Wfc: 1024*256 = 262144 elements
        const size_t e = ((size_t)(bid - 4096) * 256 + threadIdx.x) * 4;
        float4 v = *(const float4*)(Wfc + e);
        ushort4 h, l;
        split1(v.x, h.x, l.x); split1(v.y, h.y, l.y);
        split1(v.z, h.z, l.z); split1(v.w, h.w, l.w);
        *(ushort4*)((unsigned short*)whi + e) = h;
        *(ushort4*)((unsigned short*)wlo + e) = l;
    }
}

// ---------------------------------------------------------------------------
// Kernel 1: U = A @ W^T + b via bf16-split MFMA.
// Logical K' = 768: [A_hi|A_hi|A_lo] x [W_hi|W_lo|W_hi].
// 128x128 tile, BK=32, 4 waves (2x2 of 64x64), mfma_f32_16x16x32_bf16 4x4/wave.
// LDS subtile layout [g(4)][row(16)][8k] bf16 = 1KiB: global_load_lds writes it
// linearly (lane i -> g=i>>4,row=i&15) and frag read = ds_read_b128 @ lane*16.
// ---------------------------------------------------------------------------
#define BM 128
#define BN 128
#define BK 32
#define KT 24    // 768/32

#define GLD16(gp, lp) __builtin_amdgcn_global_load_lds( \
    (const __attribute__((address_space(1))) unsigned int*)(gp), \
    (__attribute__((address_space(3))) unsigned int*)(lp), 16, 0, 0)

__global__ __launch_bounds__(256, 4) void fc_gemm_mfma(
    const __hip_bfloat16* __restrict__ Ahi, const __hip_bfloat16* __restrict__ Alo,
    const __hip_bfloat16* __restrict__ Whi, const __hip_bfloat16* __restrict__ Wlo,
    const float* __restrict__ bfc, float* __restrict__ U)
{
    __shared__ __hip_bfloat16 lA[2][8][4][16][8];  // [buf][msub][g][row][k8]
    __shared__ __hip_bfloat16 lB[2][8][4][16][8];  // [buf][nsub][g][row][k8]

    const int t    = threadIdx.x;
    const int w    = t >> 6;
    const int lane = t & 63;
    const int m0   = blockIdx.y * BM;
    const int n0   = blockIdx.x * BN;
    const int row  = lane & 15;
    const int g    = lane >> 4;

    f32x4 acc[4][4];
#pragma unroll
    for (int i = 0; i < 4; ++i)
#pragma unroll
        for (int j = 0; j < 4; ++j) acc[i][j] = (f32x4){0.f, 0.f, 0.f, 0.f};

    auto stage = [&](int buf, int kt) {
        const __hip_bfloat16* As = (kt < 16) ? Ahi : Alo;
        const __hip_bfloat16* Bs = (kt < 8) ? Whi : ((kt < 16) ? Wlo : Whi);
        const int kp = (kt & 7) * BK;
        const int ms = 2 * w;               // this wave stages subtiles {2w, 2w+1}
        const __hip_bfloat16* ga0 = As + (size_t)(m0 + ms * 16 + row) * NI + kp + g * 8;
        const __hip_bfloat16* gb0 = Bs + (size_t)(n0 + ms * 16 + row) * NI + kp + g * 8;
        GLD16(ga0,            &lA[buf][ms][0][0][0]);
        GLD16(ga0 + 16 * NI,  &lA[buf][ms + 1][0][0][0]);
        GLD16(gb0,            &lB[buf][ms][0][0][0]);
        GLD16(gb0 + 16 * NI,  &lB[buf][ms + 1][0][0][0]);
    };

    const int wm = w >> 1, wn = w & 1;

    auto compute = [&](int buf) {
        short8 af[4], bfr[4];
#pragma unroll
        for (int f = 0; f < 4; ++f)
            af[f] = *(const short8*)((const short*)&lA[buf][wm * 4 + f][0][0][0] + lane * 8);
#pragma unroll
        for (int f = 0; f < 4; ++f)
            bfr[f] = *(const short8*)((const short*)&lB[buf][wn * 4 + f][0][0][0] + lane * 8);
#pragma unroll
        for (int fm = 0; fm < 4; ++fm)
#pragma unroll
            for (int fn = 0; fn < 4; ++fn)
                acc[fm][fn] = __builtin_amdgcn_mfma_f32_16x16x32_bf16(
                    af[fm], bfr[fn], acc[fm][fn], 0, 0, 0);
    };

    stage(0, 0);
    __syncthreads();
#pragma unroll 2
    for (int kt = 0; kt < KT; ++kt) {
        const int cur = kt & 1;
        if (kt + 1 < KT) stage(cur ^ 1, kt + 1);   // prefetch overlaps compute
        compute(cur);
        __syncthreads();                            // drains vmcnt for cur^1
    }

    // Epilogue: C/D layout col=lane&15, row=(lane>>4)*4+reg  [m89-verified]
#pragma unroll
    for (int fn = 0; fn < 4; ++fn) {
        const int gn = n0 + wn * 64 + fn * 16 + row;
        const float bias = bfc[gn];
#pragma unroll
        for (int fm = 0; fm < 4; ++fm) {
            const int gm = m0 + wm * 64 + fm * 16 + g * 4;
#pragma unroll
            for (int r = 0; r < 4; ++r)
                U[(size_t)(gm + r) * NH + gn] = acc[fm][fn][r] + bias;
        }
    }
}

// ---------------------------------------------------------------------------
// Kernel 2: per-element RK4.  tanh(u+ga*h) = 1 - 2/(1 + exp2(c*h + d)).
// ---------------------------------------------------------------------------
__device__ __forceinline__ float f_eval(float h, float c, float d, float na, float be)
{
    float z2 = fmaf(c, h, d);
#if __has_builtin(__builtin_amdgcn_exp2f)
    float e = __builtin_amdgcn_exp2f(z2);
#else
    float e = __expf(0.69314718056f * z2);
#endif
    float th = fmaf(-2.0f, __builtin_amdgcn_rcpf(e + 1.0f), 1.0f);
    return fmaf(na, h, be * th);
}

__global__ __launch_bounds__(256) void ode_kernel(
    const float* __restrict__ U, const float* __restrict__ alpha,
    const float* __restrict__ beta, const float* __restrict__ gamma,
    float* __restrict__ hout)
{
    const int idx = blockIdx.x * 256 + threadIdx.x;  // b*NH + h
    const int hid = idx & (NH - 1);
    const float na = -alpha[hid];
    const float be = beta[hid];
    const float L2E2 = 2.8853900817779268f;          // 2*log2(e)
    const float c   = L2E2 * gamma[hid];
    const float dt  = 1.0f / (float)(NS * KSUB);
    const float hdt = 0.5f * dt;
    const float dt6 = dt * (1.0f / 6.0f);

    float h = 0.f;
    float u = U[idx];
#pragma unroll 1
    for (int s = 0; s < NS; ++s) {
        const int snext = (s + 1 < NS) ? s + 1 : NS - 1;
        const float u_next = U[(size_t)snext * (NB * NH) + idx];  // prefetch
        const float d = L2E2 * u;
#pragma unroll
        for (int k = 0; k < KSUB; ++k) {
            float k1 = f_eval(h, c, d, na, be);
            float k2 = f_eval(fmaf(hdt, k1, h), c, d, na, be);
            float k3 = f_eval(fmaf(hdt, k2, h), c, d, na, be);
            float k4 = f_eval(fmaf(dt, k3, h), c, d, na, be);
            float t1 = k2 + k3;
            float t2 = k1 + k4;
            h = fmaf(dt6, fmaf(2.0f, t1, t2), h);
        }
        u = u_next;
    }
    hout[idx] = h;
}

// ---------------------------------------------------------------------------
// Kernel 3: out[b][o] = dot(h_final[b], W_out[o]) + b_out[o].
// ---------------------------------------------------------------------------
__global__ __launch_bounds__(256) void out_gemv(
    const float* __restrict__ hfin, const float* __restrict__ Wout,
    const float* __restrict__ bout, float* __restrict__ out)
{
    __shared__ float red[4][NO];
    const int b = blockIdx.x;
    const int t = threadIdx.x;

    const float h0 = hfin[b * NH + t];
    const float h1 = hfin[b * NH + t + 256];
    const float h2 = hfin[b * NH + t + 512];
    const float h3 = hfin[b * NH + t + 768];

    float acc[NO];
#pragma unroll
    for (int o = 0; o < NO; ++o) {
        const float* wr = Wout + (size_t)o * NH + t;
        acc[o] = h0 * wr[0] + h1 * wr[256] + h2 * wr[512] + h3 * wr[768];
    }
#pragma unroll
    for (int o = 0; o < NO; ++o)
#pragma unroll
        for (int off = 32; off > 0; off >>= 1)
            acc[o] += __shfl_down(acc[o], off, 64);

    const int wid = t >> 6, lane = t & 63;
    if (lane == 0)
#pragma unroll
        for (int o = 0; o < NO; ++o) red[wid][o] = acc[o];
    __syncthreads();
    if (t < NO)
        out[b * NO + t] = red[0][t] + red[1][t] + red[2][t] + red[3][t] + bout[t];
}

// ---------------------------------------------------------------------------
extern "C" void kernel_launch(void* const* d_in, const int* in_sizes, int n_in,
                              void* d_out, int out_size, void* d_ws, size_t ws_size,
                              hipStream_t stream)
{
    const float* x     = (const float*)d_in[0];
    const float* Wfc   = (const float*)d_in[1];
    const float* bfc   = (const float*)d_in[2];
    const float* alpha = (const float*)d_in[3];
    const float* beta  = (const float*)d_in[4];
    const float* gamma = (const float*)d_in[5];
    const float* Wout  = (const float*)d_in[6];
    const float* bout  = (const float*)d_in[7];
    float* out = (float*)d_out;

    // workspace: U fp32 64MiB | hfin 1MiB | xhi 8MiB | xlo 8MiB | whi .5MiB | wlo .5MiB
    float* U    = (float*)d_ws;
    float* hfin = U + (size_t)NS * NB * NH;
    __hip_bfloat16* xhi = (__hip_bfloat16*)(hfin + (size_t)NB * NH);
    __hip_bfloat16* xlo = xhi + (size_t)NS * NB * NI;
    __hip_bfloat16* whi = xlo + (size_t)NS * NB * NI;
    __hip_bfloat16* wlo = whi + (size_t)NH * NI;

    split_kernel<<<4096 + 256, 256, 0, stream>>>(x, Wfc, xhi, xlo, whi, wlo);

    dim3 g1(NH / BN, (NS * NB) / BM);   // (8, 128)
    fc_gemm_mfma<<<g1, 256, 0, stream>>>(xhi, xlo, whi, wlo, bfc, U);

    ode_kernel<<<(NB * NH) / 256, 256, 0, stream>>>(U, alpha, beta, gamma, hfin);
    out_gemv<<<NB, 256, 0, stream>>>(hfin, Wout, bout, out);
}